// Round 6
// baseline (1716.860 us; speedup 1.0000x reference)
//
#include <hip/hip_runtime.h>
#include <hip/hip_bf16.h>

// MSAColumnAttention — R6: R4 numerics (exp2f, unfolded scale) + R5 structure
// (16-wave blocks = 4 waves/SIMD, r-major dispatch). Isolates the R5 failure:
// raw v_exp_f32 inline asm lacked the backend-inserted TRANS-use wait state.
//
// 32x32x16 bf16 MFMA layouts (verified by R4 absmax):
//   A[m][k]: lane(gg,j)=gg*32+j holds row m=j, k=8gg+e ; B likewise (col n=j)
//   D[m][n]: lane(gg,j) holds col n=j, rows m=(reg&3)+8*(reg>>2)+4*gg
// Fragment construction: 8x cvt_pk + 4x permlane32_swap per D-tile (R4-verified).
//
// ws layout (total 202,117,120 B):
//   Wallbf [8][128][256] bf16 @0 | ball [1024] f32 @524288 | oWhi @528384 | oWlo @659456
//   xhat [196608][256] bf16 @790528 | obuf [196608][256] bf16 @101453824

#define S_DIM 512
#define R_DIM 384
#define CM    256
#define NH    8
#define NROWS (S_DIM*R_DIM)

typedef unsigned short u16;
typedef unsigned int   u32;
typedef short bf16x8 __attribute__((ext_vector_type(8)));
typedef float f32x4  __attribute__((ext_vector_type(4)));
typedef float f32x16 __attribute__((ext_vector_type(16)));
typedef int   v2i    __attribute__((ext_vector_type(2)));

#define MFMA16(a,b,c) __builtin_amdgcn_mfma_f32_16x16x32_bf16((a),(b),(c),0,0,0)
#define MFMA32(a,b,c) __builtin_amdgcn_mfma_f32_32x32x16_bf16((a),(b),(c),0,0,0)

__device__ __forceinline__ float lo16f(u32 u){ return __uint_as_float(u << 16); }
__device__ __forceinline__ float hi16f(u32 u){ return __uint_as_float(u & 0xffff0000u); }
__device__ __forceinline__ float b2f(u16 x){ return __uint_as_float(((u32)x) << 16); }
__device__ __forceinline__ u16 f2bf(float f){
  u32 u = __float_as_uint(f);
  return (u16)((u + 0x7fffu + ((u >> 16) & 1u)) >> 16);   // RNE
}
__device__ __forceinline__ u32 pk2(float a, float b){
  return (u32)f2bf(a) | ((u32)f2bf(b) << 16);
}
__device__ __forceinline__ u32 cvtpk(float a, float b){
  u32 d;
  asm("v_cvt_pk_bf16_f32 %0, %1, %2" : "=v"(d) : "v"(a), "v"(b));
  return d;
}
__device__ __forceinline__ v2i pl32swap(u32 a, u32 b){
  return __builtin_amdgcn_permlane32_swap((int)a, (int)b, false, false);
}
__device__ __forceinline__ f32x16 zero16(){
  f32x16 z;
  #pragma unroll
  for(int q=0;q<16;q++) z[q]=0.f;
  return z;
}

#define SC2 0.2550348653f   // (1/sqrt(32)) * log2(e), applied in f32 after QK MFMA

// ---------------------------------------------------------------- prep_w ----
__global__ void prep_w(const float* __restrict__ lnw, const float* __restrict__ lnb,
                       const float* __restrict__ Wq, const float* __restrict__ Wk,
                       const float* __restrict__ Wv, const float* __restrict__ Wg,
                       const float* __restrict__ oW,
                       float* __restrict__ ball, u16* __restrict__ Wallbf,
                       u16* __restrict__ oWhi, u16* __restrict__ oWlo){
  int blk = blockIdx.x, t = threadIdx.x;
  if (blk < 1024){
    int h = blk >> 7, row = blk & 127, mat = row >> 5, c = row & 31;
    const float* Ws = (mat==0?Wq: mat==1?Wk: mat==2?Wv:Wg) + (size_t)(h*32+c)*CM;
    float4 w4 = ((const float4*)Ws)[t];
    float4 l4 = ((const float4*)(lnw + (size_t)h*CM))[t];
    float4 b4 = ((const float4*)(lnb + (size_t)h*CM))[t];
    ((uint2*)(Wallbf + (size_t)blk*CM))[t] =
        make_uint2(pk2(w4.x*l4.x, w4.y*l4.y), pk2(w4.z*l4.z, w4.w*l4.w));
    float p = w4.x*b4.x + w4.y*b4.y + w4.z*b4.z + w4.w*b4.w;
    #pragma unroll
    for(int off=32; off; off>>=1) p += __shfl_down(p, off);
    if(t==0) ball[blk] = p;
  } else {
    int m = blk - 1024;
    float4 w4 = ((const float4*)(oW + (size_t)m*CM))[t];
    u16 h0=f2bf(w4.x), h1=f2bf(w4.y), h2=f2bf(w4.z), h3=f2bf(w4.w);
    u16 l0=f2bf(w4.x-b2f(h0)), l1=f2bf(w4.y-b2f(h1));
    u16 l2=f2bf(w4.z-b2f(h2)), l3=f2bf(w4.w-b2f(h3));
    ((uint2*)(oWhi + (size_t)m*CM))[t] = make_uint2((u32)h0|((u32)h1<<16), (u32)h2|((u32)h3<<16));
    ((uint2*)(oWlo + (size_t)m*CM))[t] = make_uint2((u32)l0|((u32)l1<<16), (u32)l2|((u32)l3<<16));
  }
}

// ---------------------------------------------------------------- ln_xhat ----
__global__ __launch_bounds__(256) void ln_xhat(const float* __restrict__ msa,
                                               u16* __restrict__ xhat){
  const int tid = threadIdx.x;
  const int n0 = blockIdx.x*64;
  const int i = tid >> 2, p = tid & 3;
  const int n = n0 + i, rr = n >> 9, s = n & 511;
  const float* src = msa + ((size_t)s*R_DIM + rr)*CM + p*64;
  float x[64]; float sum=0.f, sq=0.f;
  #pragma unroll
  for(int j=0;j<64;j+=4){
    float4 v = *(const float4*)(src + j);
    x[j]=v.x; x[j+1]=v.y; x[j+2]=v.z; x[j+3]=v.w;
    sum += v.x+v.y+v.z+v.w;
    sq  += v.x*v.x + v.y*v.y + v.z*v.z + v.w*v.w;
  }
  sum += __shfl_xor(sum,1); sum += __shfl_xor(sum,2);
  sq  += __shfl_xor(sq,1);  sq  += __shfl_xor(sq,2);
  float mu = sum*(1.f/256.f);
  float rs = rsqrtf(sq*(1.f/256.f) - mu*mu + 1e-5f);
  u16* dst = xhat + (size_t)n*CM + p*64;
  #pragma unroll
  for(int j=0;j<64;j+=2)
    *(u32*)(dst + j) = pk2((x[j]-mu)*rs, (x[j+1]-mu)*rs);
}

// --------------------------------------------------------------- attn_fused3 ----
// 16 waves. proj: wave -> mat=w>>2, 4 s-tiles. phase1: wave -> t-tile w.
// phase2+epilogue: wave -> s-tile w.
// LDS: Qf/Kf/Vf [16 tile][2 T][64 lane][16B] (32KB each); Gf [16][64][32B]; ivd f32[512]
#define QF   0
#define KF   32768
#define VF   65536
#define GF   98304
#define IVD  131072
#define ATTN_LDS 133120

__global__ __launch_bounds__(1024,1) void attn_fused3(const u16* __restrict__ xhat,
      const u16* __restrict__ Wallbf, const float* __restrict__ ball,
      u16* __restrict__ obuf){
  extern __shared__ char sm[];
  const int bid  = blockIdx.x;
  const int head = bid & 7;              // r-major: 8 heads of one r co-resident
  const int r    = bid >> 3;
  const int tid  = threadIdx.x;
  const int w    = tid >> 6;
  const int lane = tid & 63;
  const int gg = lane >> 5, j = lane & 31;
  const int n0 = r * 512;

  // ================= proj: D = W·xhat^T (Q,K,G) / xhat·Wv^T (V) =================
  {
    const int mat = w >> 2;
    const u16* wrow = Wallbf + ((size_t)(head*128 + mat*32 + j))*CM + gg*8;
    bf16x8 Wf[16];
    #pragma unroll
    for(int kc=0;kc<16;kc++) Wf[kc] = *(const bf16x8*)(wrow + kc*16);
    float bias16[16]; float biasv = 0.f;
    if (mat == 2) biasv = ball[head*128 + 64 + j];
    else {
      #pragma unroll
      for(int reg=0;reg<16;reg++)
        bias16[reg] = ball[head*128 + mat*32 + (reg&3) + 8*(reg>>2) + 4*gg];
    }
    char* outbase = sm + (mat==0? QF : mat==1? KF : VF);
    for(int st=0; st<4; st++){
      const int stg = (w&3)*4 + st;
      const u16* xr = xhat + ((size_t)(n0 + stg*32 + j))*CM + gg*8;
      f32x16 D = zero16();
      if (mat == 2){
        #pragma unroll
        for(int kc=0;kc<16;kc++) D = MFMA32(*(const bf16x8*)(xr + kc*16), Wf[kc], D);
      } else {
        #pragma unroll
        for(int kc=0;kc<16;kc++) D = MFMA32(Wf[kc], *(const bf16x8*)(xr + kc*16), D);
      }
      if (mat == 3){                       // G: sigmoid, store raw D-layout bf16
        u32 gw[8];
        #pragma unroll
        for(int p=0;p<4;p++)
          #pragma unroll
          for(int hh=0;hh<2;hh++){
            float a = D[4*p+2*hh]   + bias16[4*p+2*hh];
            float b = D[4*p+2*hh+1] + bias16[4*p+2*hh+1];
            float sa = 1.f/(1.f + __expf(-a));
            float sb = 1.f/(1.f + __expf(-b));
            gw[p*2+hh] = cvtpk(sa, sb);
          }
        u32* gd = (u32*)(sm + GF + ((size_t)stg*64 + lane)*32);
        *(uint4*)gd     = make_uint4(gw[0],gw[1],gw[2],gw[3]);
        *(uint4*)(gd+4) = make_uint4(gw[4],gw[5],gw[6],gw[7]);
      } else {
        if (mat == 2){
          #pragma unroll
          for(int q=0;q<16;q++) D[q] += biasv;
        } else {
          #pragma unroll
          for(int q=0;q<16;q++) D[q] += bias16[q];
        }
        u32 Wd[8];
        #pragma unroll
        for(int p=0;p<4;p++)
          #pragma unroll
          for(int hh=0;hh<2;hh++)
            Wd[p*2+hh] = cvtpk(D[4*p+2*hh], D[4*p+2*hh+1]);
        #pragma unroll
        for(int T=0;T<2;T++){
          u32 frag[4];
          #pragma unroll
          for(int hh=0;hh<2;hh++){
            v2i res = pl32swap(Wd[4*T+hh], Wd[4*T+2+hh]);
            frag[hh] = (u32)res[0]; frag[2+hh] = (u32)res[1];
          }
          *(uint4*)(outbase + ((size_t)(stg*2+T)*64 + lane)*16) =
              make_uint4(frag[0],frag[1],frag[2],frag[3]);
        }
      }
    }
  }
  __syncthreads();

  // ================= phase 1: d[t] = sum_s exp(SC*l[s,t]) ; ivd = 1/d =========
  {
    bf16x8 Kf0 = *(const bf16x8*)(sm + KF + ((size_t)(w*2+0)*64 + lane)*16);
    bf16x8 Kf1 = *(const bf16x8*)(sm + KF + ((size_t)(w*2+1)*64 + lane)*16);
    float dacc = 0.f;
    for(int st=0; st<16; st++){
      bf16x8 q0 = *(const bf16x8*)(sm + QF + ((size_t)(st*2+0)*64 + lane)*16);
      bf16x8 q1 = *(const bf16x8*)(sm + QF + ((size_t)(st*2+1)*64 + lane)*16);
      f32x16 A = zero16();
      A = MFMA32(q0, Kf0, A); A = MFMA32(q1, Kf1, A);
      float s0=0.f;
      #pragma unroll
      for(int q=0;q<16;q++) s0 += exp2f(A[q]*SC2);
      dacc += s0;
    }
    v2i r0 = pl32swap(__float_as_uint(dacc), __float_as_uint(dacc));
    float tot = __uint_as_float((u32)r0[0]) + __uint_as_float((u32)r0[1]);
    float* ivd = (float*)(sm + IVD);
    if (lane < 32) ivd[w*32 + j] = 1.f/tot;
  }
  __syncthreads();

  // ================= scale V-frags by ivd[t] ====================================
  {
    const float* ivd = (const float*)(sm + IVD);
    #pragma unroll
    for(int it=0; it<2; it++){
      int ch = tid + it*1024;
      int t0 = (ch>>7)*32 + ((ch>>6)&1)*16 + ((ch>>5)&1)*8;
      u32* pw = (u32*)(sm + VF + (size_t)ch*16);
      uint4 v = *(uint4*)pw;
      u32 wv[4] = {v.x, v.y, v.z, v.w};
      u32 nw[4];
      #pragma unroll
      for(int rr2=0;rr2<4;rr2++){
        float lo = lo16f(wv[rr2]) * ivd[t0 + 2*rr2];
        float hi = hi16f(wv[rr2]) * ivd[t0 + 2*rr2 + 1];
        nw[rr2] = cvtpk(lo, hi);
      }
      *(uint4*)pw = make_uint4(nw[0],nw[1],nw[2],nw[3]);
    }
  }
  __syncthreads();

  // ================= phase 2: O^T = Vt^T · exp(L^T) ; gate; store ==============
  {
    bf16x8 Qf0 = *(const bf16x8*)(sm + QF + ((size_t)(w*2+0)*64 + lane)*16);
    bf16x8 Qf1 = *(const bf16x8*)(sm + QF + ((size_t)(w*2+1)*64 + lane)*16);
    f32x16 O = zero16();
    for(int tt=0; tt<16; tt++){
      bf16x8 Kt0 = *(const bf16x8*)(sm + KF + ((size_t)(tt*2+0)*64 + lane)*16);
      bf16x8 Kt1 = *(const bf16x8*)(sm + KF + ((size_t)(tt*2+1)*64 + lane)*16);
      bf16x8 Vt0 = *(const bf16x8*)(sm + VF + ((size_t)(tt*2+0)*64 + lane)*16);
      bf16x8 Vt1 = *(const bf16x8*)(sm + VF + ((size_t)(tt*2+1)*64 + lane)*16);
      f32x16 D = zero16();
      D = MFMA32(Kt0, Qf0, D);      // D[t'][s'] accumulate over c
      D = MFMA32(Kt1, Qf1, D);
      u32 Wd[8];
      #pragma unroll
      for(int p=0;p<4;p++)
        #pragma unroll
        for(int hh=0;hh<2;hh++)
          Wd[p*2+hh] = cvtpk(exp2f(D[4*p+2*hh]*SC2), exp2f(D[4*p+2*hh+1]*SC2));
      union { u32 wu[4]; bf16x8 v; } pf0, pf1;
      #pragma unroll
      for(int hh=0;hh<2;hh++){
        v2i res = pl32swap(Wd[0+hh], Wd[2+hh]);
        pf0.wu[hh] = (u32)res[0]; pf0.wu[2+hh] = (u32)res[1];
        v2i res2 = pl32swap(Wd[4+hh], Wd[6+hh]);
        pf1.wu[hh] = (u32)res2[0]; pf1.wu[2+hh] = (u32)res2[1];
      }
      O = MFMA32(Vt0, pf0.v, O);
      O = MFMA32(Vt1, pf1.v, O);
    }
    // epilogue: gate + bf16 store (wave w -> s-tile w)
    const u32* gd = (const u32*)(sm + GF + ((size_t)w*64 + lane)*32);
    uint4 ga = *(const uint4*)gd, gb = *(const uint4*)(gd+4);
    u32 g[8] = {ga.x,ga.y,ga.z,ga.w, gb.x,gb.y,gb.z,gb.w};
    int srow = n0 + w*32 + j;
    u32* ob32 = (u32*)(obuf + (size_t)srow*CM + head*32);
    #pragma unroll
    for(int p=0;p<4;p++)
      #pragma unroll
      for(int hh=0;hh<2;hh++){
        float o0 = O[4*p+2*hh]   * lo16f(g[p*2+hh]);
        float o1 = O[4*p+2*hh+1] * hi16f(g[p*2+hh]);
        ob32[4*p + 2*gg + hh] = cvtpk(o0, o1);
      }
  }
}

// --------------------------------------------------------------- outproj ----
__global__ __launch_bounds__(256,2) void outproj(const u16* __restrict__ obuf,
      const u16* __restrict__ oWhi, const u16* __restrict__ oWlo,
      const float* __restrict__ ob, float* __restrict__ out){
  const int tid = threadIdx.x, w = tid>>6, lane = tid&63, g = lane>>4, i = lane&15;
  const int n0 = blockIdx.x*64 + w*16;
  const char* ab = (const char*)(obuf + (size_t)(n0 + i)*CM);
  const f32x4 zf = {0.f,0.f,0.f,0.f};
  f32x4 acc[16];
  #pragma unroll
  for(int ct=0;ct<16;ct++) acc[ct] = zf;
  #pragma unroll
  for(int kk=0; kk<8; kk++){
    bf16x8 a = *(const bf16x8*)(ab + kk*64 + g*16);
    #pragma unroll
    for(int ct=0; ct<16; ct++){
      const char* wh = (const char*)(oWhi + (size_t)(ct*16 + i)*CM);
      const char* wl = (const char*)(oWlo + (size_t)(ct*16 + i)*CM);
      bf16x8 bh = *(const bf16x8*)(wh + kk*64 + g*16);
      bf16x8 bl = *(const bf16x8*)(wl + kk*64 + g*16);
      acc[ct] = MFMA16(a, bh, acc[ct]);
      acc[ct] = MFMA16(a, bl, acc[ct]);
    }
  }
  #pragma unroll
  for(int ct=0; ct<16; ct++){
    float bias = ob[ct*16 + i];
    #pragma unroll
    for(int q=0; q<4; q++){
      int n = n0 + 4*g + q;
      out[((size_t)(n & 511)*R_DIM + (n >> 9))*CM + ct*16 + i] = acc[ct][q] + bias;
    }
  }
}

// ------------------------------------------------------------------ host ----
extern "C" void kernel_launch(void* const* d_in, const int* in_sizes, int n_in,
                              void* d_out, int out_size, void* d_ws, size_t ws_size,
                              hipStream_t stream){
  const float* msa = (const float*)d_in[0];
  const float* lnw = (const float*)d_in[1];
  const float* lnb = (const float*)d_in[2];
  const float* Wq  = (const float*)d_in[3];
  const float* Wk  = (const float*)d_in[4];
  const float* Wv  = (const float*)d_in[5];
  const float* Wg  = (const float*)d_in[6];
  const float* oW  = (const float*)d_in[7];
  const float* ob  = (const float*)d_in[8];
  float* out = (float*)d_out;

  char* ws = (char*)d_ws;
  u16*   Wallbf = (u16*)(ws);
  float* ball   = (float*)(ws + 524288);
  u16*   oWhi   = (u16*)(ws + 528384);
  u16*   oWlo   = (u16*)(ws + 659456);
  u16*   xhat   = (u16*)(ws + 790528);
  u16*   obuf   = (u16*)(ws + 101453824);

  (void)hipFuncSetAttribute((const void*)attn_fused3,
                      hipFuncAttributeMaxDynamicSharedMemorySize, ATTN_LDS);

  prep_w<<<dim3(1280), dim3(64), 0, stream>>>(lnw, lnb, Wq, Wk, Wv, Wg, oW,
                                              ball, Wallbf, oWhi, oWlo);
  ln_xhat<<<dim3(NROWS/64), dim3(256), 0, stream>>>(msa, xhat);
  attn_fused3<<<dim3(R_DIM*NH), dim3(1024), ATTN_LDS, stream>>>(xhat, Wallbf, ball, obuf);
  outproj<<<dim3(NROWS/64), dim3(256), 0, stream>>>(obuf, oWhi, oWlo, ob, out);
}